// Round 2
// 136.080 us; speedup vs baseline: 1.0164x; 1.0164x over previous
//
#include <hip/hip_runtime.h>

#define BATCH 8
#define CH 512
#define C16 32
#define W 64
#define HWSZ 4096   // 64*64
#define NCH 4096    // BATCH*CH
#define LDS_STRIDE 68  // 64 + 4 pad: spreads banks for stride-16 float4 access

#define NEG_INF (-__builtin_inff())

// ---------------- Kernel A: per-channel global average pool ----------------
__global__ __launch_bounds__(256) void gap_kernel(const float* __restrict__ x,
                                                  float* __restrict__ gap) {
    const int chan = blockIdx.x;
    const float* xp = x + (size_t)chan * HWSZ;
    const int t = threadIdx.x;
    float sum = 0.f;
#pragma unroll
    for (int j = 0; j < 4; ++j) {
        const float4 f = *(const float4*)(xp + t * 4 + j * 1024);
        sum += f.x + f.y + f.z + f.w;
    }
#pragma unroll
    for (int off = 32; off > 0; off >>= 1) sum += __shfl_down(sum, off, 64);
    __shared__ float ws[4];
    if ((t & 63) == 0) ws[t >> 6] = sum;
    __syncthreads();
    if (t == 0) {
        gap[chan] = (ws[0] + ws[1] + ws[2] + ws[3]) * (1.0f / HWSZ);
    }
}

// ---------------- Kernel B: SE bottleneck -> routing score s ----------------
__global__ __launch_bounds__(256) void score_kernel(const float* __restrict__ gap,
                                                    const float* __restrict__ w1,
                                                    const float* __restrict__ b1,
                                                    const float* __restrict__ w2,
                                                    const float* __restrict__ b2,
                                                    float* __restrict__ s_out) {
    const int b = blockIdx.x;   // one block per batch
    const int t = threadIdx.x;
    __shared__ float g[CH];
    __shared__ float partial[C16][9];  // +1 pad
    __shared__ float hmid[C16];
    g[t] = gap[b * CH + t];
    g[t + 256] = gap[b * CH + t + 256];
    __syncthreads();
    const int e = t >> 3, part = t & 7;
    float p = 0.f;
    const int j0 = part * 64;
    for (int j = 0; j < 64; ++j) p += g[j0 + j] * w1[e * CH + j0 + j];
    partial[e][part] = p;
    __syncthreads();
    if (t < C16) {
        float acc = b1[t];
#pragma unroll
        for (int j = 0; j < 8; ++j) acc += partial[t][j];
        hmid[t] = fmaxf(acc, 0.f);
    }
    __syncthreads();
#pragma unroll
    for (int ci = 0; ci < 2; ++ci) {
        const int c = t + ci * 256;
        float acc = b2[c];
#pragma unroll
        for (int e2 = 0; e2 < C16; ++e2) acc += hmid[e2] * w2[c * C16 + e2];
        s_out[b * CH + c] = fmaxf(acc, 0.f);  // expend_num_relu
    }
}

// ---------------- Kernel C: routed dual maxpool + blend + residual ----------------
__device__ __forceinline__ float4 max4(float4 a, float4 b) {
    return make_float4(fmaxf(a.x, b.x), fmaxf(a.y, b.y), fmaxf(a.z, b.z), fmaxf(a.w, b.w));
}
__device__ __forceinline__ float max3f(float a, float b, float c) {
    return fmaxf(fmaxf(a, b), c);  // clang folds to v_max3_f32
}

// level needed for half-width h: smallest L with 2^L >= h+1
constexpr int lvl(int h) { return h <= 0 ? 0 : (h <= 1 ? 1 : (h <= 3 ? 2 : 3)); }

// Horizontal: v[32] covers row positions [seg*16-8, seg*16+24); outputs 16 px
// of the half-Q window max ONLY (the Q+1 plane is derived in phase 2 by dilation).
template <int Q>
__device__ __forceinline__ void hpool_s(const float v[32], float os[16]) {
    constexpr int LS = lvl(Q);
    float m2[31], m4[29], m8[25];
    if constexpr (LS >= 1) {
#pragma unroll
        for (int j = 0; j < 31; ++j) m2[j] = fmaxf(v[j], v[j + 1]);
    }
    if constexpr (LS >= 2) {
#pragma unroll
        for (int j = 0; j < 29; ++j) m4[j] = fmaxf(m2[j], m2[j + 2]);
    }
    if constexpr (LS >= 3) {
#pragma unroll
        for (int j = 0; j < 25; ++j) m8[j] = fmaxf(m4[j], m4[j + 4]);
    }
#pragma unroll
    for (int i = 0; i < 16; ++i) {
        const int pos = 8 + i;
        constexpr int P = 1 << LS;
        const int a = pos - Q, b = pos + Q - P + 1;
        if constexpr (LS == 0) os[i] = v[pos];
        else if constexpr (LS == 1) os[i] = fmaxf(m2[a], m2[b]);
        else if constexpr (LS == 2) os[i] = fmaxf(m4[a], m4[b]);
        else os[i] = fmaxf(m8[a], m8[b]);
    }
}

// Vertical over hs rows, SHARED pyramid: v[16] covers rows [y0-6, y0+9].
// os4 = vertical half-Q max (s branch, final).
// pre4 = vertical half-(Q+1) max of the UNdilated hs columns (b branch needs a
//        final horizontal +-1 dilation, done by the caller via lane shuffles —
//        valid because column dilation commutes with the row max).
template <int Q>
__device__ __forceinline__ void vcomb2(const float4 v[16], float4 os4[4], float4 pre4[4]) {
    constexpr int LS = lvl(Q);
    constexpr int LB = lvl(Q + 1);  // LB >= LS always
    float4 m2[15], m4[13], m8[9];
    if constexpr (LB >= 1) {
#pragma unroll
        for (int j = 0; j < 15; ++j) m2[j] = max4(v[j], v[j + 1]);
    }
    if constexpr (LB >= 2) {
#pragma unroll
        for (int j = 0; j < 13; ++j) m4[j] = max4(m2[j], m2[j + 2]);
    }
    if constexpr (LB >= 3) {
#pragma unroll
        for (int j = 0; j < 9; ++j) m8[j] = max4(m4[j], m4[j + 4]);
    }
#pragma unroll
    for (int i = 0; i < 4; ++i) {
        const int pos = 6 + i;
        {   // s branch: half Q at level LS
            constexpr int P = 1 << LS;
            const int a = pos - Q, b = pos + Q - P + 1;
            if constexpr (LS == 0) os4[i] = v[pos];
            else if constexpr (LS == 1) os4[i] = max4(m2[a], m2[b]);
            else if constexpr (LS == 2) os4[i] = max4(m4[a], m4[b]);
            else os4[i] = max4(m8[a], m8[b]);
        }
        {   // b branch pre: half Q+1 at level LB (same pyramid!)
            constexpr int HH = Q + 1;
            constexpr int P = 1 << LB;
            const int a = pos - HH, b = pos + HH - P + 1;
            if constexpr (LB == 1) pre4[i] = max4(m2[a], m2[b]);
            else if constexpr (LB == 2) pre4[i] = max4(m4[a], m4[b]);
            else pre4[i] = max4(m8[a], m8[b]);
        }
    }
}

template <int Q>
__device__ __forceinline__ void pool_body(const float v[32], float* hs,
                                          const float* __restrict__ xp,
                                          float* __restrict__ op, float fb, float fs) {
    const int t = threadIdx.x;
    const int r = t >> 2, seg = t & 3;
    float os[16];
    hpool_s<Q>(v, os);
    float* hsp = hs + r * LDS_STRIDE + seg * 16;
#pragma unroll
    for (int j = 0; j < 4; ++j) {
        *(float4*)(hsp + 4 * j) = make_float4(os[4*j], os[4*j+1], os[4*j+2], os[4*j+3]);
    }
    __syncthreads();
    const int cg = t & 15, rb = t >> 4;
    const int x0 = cg * 4, y0 = rb * 4;
    float4 av[16];
#pragma unroll
    for (int j = 0; j < 16; ++j) {
        int row = y0 - 6 + j;
        row = row < 0 ? 0 : (row > 63 ? 63 : row);  // clamp == SAME pad for max
        av[j] = *(const float4*)(hs + row * LDS_STRIDE + x0);
    }
    float4 vs4[4], pre4[4];
    vcomb2<Q>(av, vs4, pre4);
#pragma unroll
    for (int i = 0; i < 4; ++i) {
        const float4 pre = pre4[i];
        // horizontal +-1 dilation: neighbor columns come from adjacent lanes.
        float lp = __shfl_up(pre.w, 1);    // col x0-1 (left lane's .w)
        float rp = __shfl_down(pre.x, 1);  // col x0+4 (right lane's .x)
        if (cg == 0) lp = pre.x;           // clamp at image edge (SAME pad)
        if (cg == 15) rp = pre.w;
        float4 vb;
        vb.x = max3f(lp,    pre.x, pre.y);
        vb.y = max3f(pre.x, pre.y, pre.z);
        vb.z = max3f(pre.y, pre.z, pre.w);
        vb.w = max3f(pre.z, pre.w, rp);
        const float4 xv = *(const float4*)(xp + (y0 + i) * W + x0);
        float4 o;
        o.x = fb * vb.x + fs * vs4[i].x + xv.x;
        o.y = fb * vb.y + fs * vs4[i].y + xv.y;
        o.z = fb * vb.z + fs * vs4[i].z + xv.z;
        o.w = fb * vb.w + fs * vs4[i].w + xv.w;
        *(float4*)(op + (y0 + i) * W + x0) = o;
    }
}

__global__ __launch_bounds__(256) void pool_kernel(const float* __restrict__ x,
                                                   const float* __restrict__ s_arr,
                                                   float* __restrict__ out) {
    __shared__ float hs[64 * LDS_STRIDE];  // 17,408 B — was 69,632 with the hb plane
    const int chan = blockIdx.x;  // 0..4095, block-uniform routing -> no divergence
    const float* xp = x + (size_t)chan * HWSZ;
    float* op = out + (size_t)chan * HWSZ;
    const float s = s_arr[chan];
    int q = (int)floorf(s);
    q = q < 0 ? 0 : (q > 5 ? 5 : q);
    const float fb = s - (float)q;        // weight on larger kernel
    const float fs = (float)(q + 1) - s;  // weight on smaller kernel

    const int t = threadIdx.x;
    const int r = t >> 2, seg = t & 3;
    float v[32];
    const float* rowp = xp + r * W;
#pragma unroll
    for (int j = 0; j < 8; ++j) {
        const int p = seg * 16 - 8 + j * 4;
        if (p >= 0 && p < W) {
            const float4 f = *(const float4*)(rowp + p);
            v[4*j] = f.x; v[4*j+1] = f.y; v[4*j+2] = f.z; v[4*j+3] = f.w;
        } else {
            v[4*j] = NEG_INF; v[4*j+1] = NEG_INF; v[4*j+2] = NEG_INF; v[4*j+3] = NEG_INF;
        }
    }
    switch (q) {
        case 0: pool_body<0>(v, hs, xp, op, fb, fs); break;
        case 1: pool_body<1>(v, hs, xp, op, fb, fs); break;
        case 2: pool_body<2>(v, hs, xp, op, fb, fs); break;
        case 3: pool_body<3>(v, hs, xp, op, fb, fs); break;
        case 4: pool_body<4>(v, hs, xp, op, fb, fs); break;
        default: pool_body<5>(v, hs, xp, op, fb, fs); break;
    }
}

extern "C" void kernel_launch(void* const* d_in, const int* in_sizes, int n_in,
                              void* d_out, int out_size, void* d_ws, size_t ws_size,
                              hipStream_t stream) {
    const float* x  = (const float*)d_in[0];
    const float* w1 = (const float*)d_in[1];
    const float* b1 = (const float*)d_in[2];
    const float* w2 = (const float*)d_in[3];
    const float* b2 = (const float*)d_in[4];
    float* out = (float*)d_out;
    float* gap = (float*)d_ws;                 // 4096 floats
    float* s   = (float*)d_ws + NCH;           // 4096 floats

    gap_kernel<<<NCH, 256, 0, stream>>>(x, gap);
    score_kernel<<<BATCH, 256, 0, stream>>>(gap, w1, b1, w2, b2, s);
    pool_kernel<<<NCH, 256, 0, stream>>>(x, s, out);
}